// Round 14
// baseline (1488.978 us; speedup 1.0000x reference)
//
#include <hip/hip_runtime.h>
#include <hip/hip_fp16.h>

#define NN 100000
#define NE 1000000
#define DD 64

typedef __attribute__((ext_vector_type(8)))  _Float16 half8;
typedef __attribute__((ext_vector_type(4)))  _Float16 half4_t;
typedef __attribute__((ext_vector_type(2)))  _Float16 half2_t;
typedef __attribute__((ext_vector_type(16))) float    f32x16;

// packed f16 atomic add — verified rounds 7/9 (absmax 2e-3).
__device__ __forceinline__ void pk_atomic_add(_Float16* p, float a, float b) {
    half2_t v = { (_Float16)a, (_Float16)b };
    asm volatile("global_atomic_pk_add_f16 %0, %1, off"
                 :: "v"(p), "v"(v) : "memory");
}

__device__ __forceinline__ half8 cvt8(const float4 a, const float4 b) {
    half8 v;
    v[0]=(_Float16)a.x; v[1]=(_Float16)a.y; v[2]=(_Float16)a.z; v[3]=(_Float16)a.w;
    v[4]=(_Float16)b.x; v[5]=(_Float16)b.y; v[6]=(_Float16)b.z; v[7]=(_Float16)b.w;
    return v;
}

// ---------------------------------------------------------------- deg count
__global__ __launch_bounds__(256) void k_count(const int* __restrict__ tgt,
                                               float* __restrict__ deg) {
    int i = blockIdx.x * blockDim.x + threadIdx.x;
    if (i < NE) atomicAdd(&deg[tgt[i]], 1.0f);
}

// ------------------------------------------------------------ convert x f16
__global__ __launch_bounds__(256) void k_cvtx(const float* __restrict__ src,
                                              _Float16* __restrict__ dst) {
    int i = blockIdx.x * 256 + threadIdx.x;
    if (i < NN * 16) {
        float4 v = ((const float4*)src)[i];
        half4_t o = { (_Float16)v.x, (_Float16)v.y, (_Float16)v.z, (_Float16)v.w };
        ((half4_t*)dst)[i] = o;
    }
}

// ----------------------------- weights → f16 MFMA-FRAGMENT layout in global
// frag f = kk*2+c, element (lane, i):  Wf[f*512 + lane*8 + i]
//   = W[(kk*16 + (lane>>5)*8 + i)*64 + 2*(lane&31) + c]
// One 16B load per frag per lane in the hot kernels; L2-resident.
__global__ __launch_bounds__(256) void k_cvtw(
    const float* __restrict__ msgW, const float* __restrict__ aggW,
    const float* __restrict__ eupW,
    _Float16* __restrict__ mWf, _Float16* __restrict__ aWf,
    _Float16* __restrict__ eWf)
{
    int idx = blockIdx.x * 256 + threadIdx.x;
    if (idx < 3 * 16 * 512) {                      // msg/agg: K=128 → 16 frags
        int l = idx / (16 * 512), rem = idx % (16 * 512);
        int f = rem / 512, e = rem % 512;
        int lane = e >> 3, i = e & 7;
        int kk = f >> 1, c = f & 1, hi = lane >> 5, lr = lane & 31;
        int src = (l * 128 + kk * 16 + hi * 8 + i) * 64 + 2 * lr + c;
        mWf[idx] = (_Float16)msgW[src];
        aWf[idx] = (_Float16)aggW[src];
    }
    if (idx < 3 * 24 * 512) {                      // eup: K=192 → 24 frags
        int l = idx / (24 * 512), rem = idx % (24 * 512);
        int f = rem / 512, e = rem % 512;
        int lane = e >> 3, i = e & 7;
        int kk = f >> 1, c = f & 1, hi = lane >> 5, lr = lane & 31;
        eWf[idx] = (_Float16)eupW[(l * 192 + kk * 16 + hi * 8 + i) * 64 + 2 * lr + c];
    }
}

// ------------------------------------------------- message matvec + scatter
// B-frags read from global frag-layout (L2-hot) each tile → low VGPR,
// high occupancy. No LDS at all.
template<int EAF32>
__global__ __launch_bounds__(256, 4) void k_msg(
    const _Float16* __restrict__ x, const void* __restrict__ ea_,
    const int* __restrict__ ei,
    const _Float16* __restrict__ Wf, const float* __restrict__ bias,
    _Float16* __restrict__ agg)
{
    const int lane = threadIdx.x & 63;
    const int hi   = lane >> 5;
    const int lr   = lane & 31;

    const float bl0 = bias[2 * lr], bl1 = bias[2 * lr + 1];

    const int nw  = (gridDim.x * blockDim.x) >> 6;
    const int wid = (blockIdx.x * blockDim.x + threadIdx.x) >> 6;

    for (int t = wid; t < NE / 32; t += nw) {
        const int e0 = t * 32;
        const int sn = ei[e0 + lr];
        const int tn = ei[NE + e0 + lr];

        half8 A[8];
#pragma unroll
        for (int kk = 0; kk < 8; ++kk) {
            if (kk < 4) {
                A[kk] = *(const half8*)(x + (size_t)sn * 64 + kk * 16 + hi * 8);
            } else if (EAF32) {
                const float* p = (const float*)ea_ + (size_t)(e0 + lr) * 64
                                 + (kk - 4) * 16 + hi * 8;
                A[kk] = cvt8(*(const float4*)p, *(const float4*)(p + 4));
            } else {
                A[kk] = *(const half8*)((const _Float16*)ea_
                                        + (size_t)(e0 + lr) * 64 + (kk - 4) * 16 + hi * 8);
            }
        }

        f32x16 C0 = {}, C1 = {};
#pragma unroll
        for (int kk = 0; kk < 8; ++kk) {
            half8 b0 = *(const half8*)(Wf + (kk * 2 + 0) * 512 + lane * 8);
            half8 b1 = *(const half8*)(Wf + (kk * 2 + 1) * 512 + lane * 8);
            C0 = __builtin_amdgcn_mfma_f32_32x32x16_f16(A[kk], b0, C0, 0, 0, 0);
            C1 = __builtin_amdgcn_mfma_f32_32x32x16_f16(A[kk], b1, C1, 0, 0, 0);
        }

#pragma unroll
        for (int r = 0; r < 16; ++r) {
            const int row = (r & 3) + 8 * (r >> 2) + 4 * hi;
            const int t2  = __shfl(tn, row);
            pk_atomic_add(agg + (size_t)t2 * 64 + 2 * lr,
                          fmaxf(C0[r] + bl0, 0.f), fmaxf(C1[r] + bl1, 0.f));
        }
    }
}

// --------------------------------------- FUSED edge-update + next-layer msg
// LDS = 16 KB (wave-private C→A transpose only, no barriers).
// B-frags from global frag-layout (L2-hot).
template<int EAF32, int WRITE_EA>
__global__ __launch_bounds__(256, 4) void k_eupmsg(
    const _Float16* __restrict__ x, const void* __restrict__ ea_,
    const int* __restrict__ ei,
    const _Float16* __restrict__ eWf, const float* __restrict__ eb,
    const _Float16* __restrict__ mWf, const float* __restrict__ mb,
    _Float16* __restrict__ eaout, _Float16* __restrict__ agg)
{
    __shared__ __attribute__((aligned(16))) _Float16 sT[4][32 * 64]; // 4KB/wave

    const int lane = threadIdx.x & 63;
    const int wv   = threadIdx.x >> 6;
    const int hi   = lane >> 5;
    const int lr   = lane & 31;

    const float ebl0 = eb[2 * lr], ebl1 = eb[2 * lr + 1];
    const float mbl0 = mb[2 * lr], mbl1 = mb[2 * lr + 1];

    char* myT = (char*)(&sT[wv][0]);
    const int nw  = (gridDim.x * blockDim.x) >> 6;
    const int wid = (blockIdx.x * blockDim.x + threadIdx.x) >> 6;

    for (int t = wid; t < NE / 32; t += nw) {
        const int e0 = t * 32;
        const int sn = ei[e0 + lr];
        const int tn = ei[NE + e0 + lr];

        half8 As[4], At[4], Ae[4];
#pragma unroll
        for (int kk = 0; kk < 4; ++kk) {
            As[kk] = *(const half8*)(x + (size_t)sn * 64 + kk * 16 + hi * 8);
            At[kk] = *(const half8*)(x + (size_t)tn * 64 + kk * 16 + hi * 8);
            if (EAF32) {
                const float* p = (const float*)ea_ + (size_t)(e0 + lr) * 64
                                 + kk * 16 + hi * 8;
                Ae[kk] = cvt8(*(const float4*)p, *(const float4*)(p + 4));
            } else {
                Ae[kk] = *(const half8*)((const _Float16*)ea_
                                         + (size_t)(e0 + lr) * 64 + kk * 16 + hi * 8);
            }
        }

        // ---- edge-update MFMA (K = 192)
        f32x16 C0 = {}, C1 = {};
#pragma unroll
        for (int kk = 0; kk < 12; ++kk) {
            half8 a = (kk < 4) ? As[kk] : (kk < 8) ? At[kk - 4] : Ae[kk - 8];
            half8 b0 = *(const half8*)(eWf + (kk * 2 + 0) * 512 + lane * 8);
            half8 b1 = *(const half8*)(eWf + (kk * 2 + 1) * 512 + lane * 8);
            C0 = __builtin_amdgcn_mfma_f32_32x32x16_f16(a, b0, C0, 0, 0, 0);
            C1 = __builtin_amdgcn_mfma_f32_32x32x16_f16(a, b1, C1, 0, 0, 0);
        }

        // epilogue: relu+bias → ea_next; store + XOR-swizzled LDS transpose
#pragma unroll
        for (int r = 0; r < 16; ++r) {
            const int row = (r & 3) + 8 * (r >> 2) + 4 * hi;
            half2_t o = { (_Float16)fmaxf(C0[r] + ebl0, 0.f),
                          (_Float16)fmaxf(C1[r] + ebl1, 0.f) };
            if (WRITE_EA)
                *(half2_t*)(eaout + (size_t)(e0 + row) * 64 + 2 * lr) = o;
            *(half2_t*)(myT + row * 128 + ((4 * lr) ^ ((row & 7) << 4))) = o;
        }
        // read back in A-frag layout (same-wave ds dependency)
        half8 Ap[4];
#pragma unroll
        for (int kk2 = 0; kk2 < 4; ++kk2) {
            const int boff = kk2 * 32 + hi * 16;
            Ap[kk2] = *(const half8*)(myT + lr * 128 + (boff ^ ((lr & 7) << 4)));
        }

        // ---- next-layer message MFMA (K = 128) + scatter
        f32x16 D0 = {}, D1 = {};
#pragma unroll
        for (int kk = 0; kk < 8; ++kk) {
            half8 a = (kk < 4) ? As[kk] : Ap[kk - 4];
            half8 b0 = *(const half8*)(mWf + (kk * 2 + 0) * 512 + lane * 8);
            half8 b1 = *(const half8*)(mWf + (kk * 2 + 1) * 512 + lane * 8);
            D0 = __builtin_amdgcn_mfma_f32_32x32x16_f16(a, b0, D0, 0, 0, 0);
            D1 = __builtin_amdgcn_mfma_f32_32x32x16_f16(a, b1, D1, 0, 0, 0);
        }
#pragma unroll
        for (int r = 0; r < 16; ++r) {
            const int row = (r & 3) + 8 * (r >> 2) + 4 * hi;
            const int t2  = __shfl(tn, row);
            pk_atomic_add(agg + (size_t)t2 * 64 + 2 * lr,
                          fmaxf(D0[r] + mbl0, 0.f), fmaxf(D1[r] + mbl1, 0.f));
        }
    }
}

// ------------------------------------------------------------- node update
__global__ __launch_bounds__(256) void k_node(
    const _Float16* __restrict__ x, const _Float16* __restrict__ agg,
    const float* __restrict__ deg,
    const _Float16* __restrict__ Wf, const float* __restrict__ bias,
    _Float16* __restrict__ xout)
{
    const int lane = threadIdx.x & 63;
    const int hi   = lane >> 5;
    const int lr   = lane & 31;

    // small kernel (3125 tiles): keep B resident in VGPRs, loaded coalesced
    half8 Bf[8][2];
    for (int kk = 0; kk < 8; ++kk)
        for (int c = 0; c < 2; ++c)
            Bf[kk][c] = *(const half8*)(Wf + (kk * 2 + c) * 512 + lane * 8);
    const float bl0 = bias[2 * lr], bl1 = bias[2 * lr + 1];

    const int nw  = (gridDim.x * blockDim.x) >> 6;
    const int wid = (blockIdx.x * blockDim.x + threadIdx.x) >> 6;

    for (int t = wid; t < NN / 32; t += nw) {
        const int n0  = t * 32;
        const float inv = 1.0f / fmaxf(deg[n0 + lr], 1.0f);
        const _Float16 ivh = (_Float16)inv;

        half8 A[8];
#pragma unroll
        for (int kk = 0; kk < 8; ++kk) {
            if (kk < 4) {
                half8 a = *(const half8*)(agg + (size_t)(n0 + lr) * 64 + kk * 16 + hi * 8);
                A[kk] = a * ivh;
            } else {
                A[kk] = *(const half8*)(x + (size_t)(n0 + lr) * 64 + (kk - 4) * 16 + hi * 8);
            }
        }

        f32x16 C0 = {}, C1 = {};
#pragma unroll
        for (int kk = 0; kk < 8; ++kk) {
            C0 = __builtin_amdgcn_mfma_f32_32x32x16_f16(A[kk], Bf[kk][0], C0, 0, 0, 0);
            C1 = __builtin_amdgcn_mfma_f32_32x32x16_f16(A[kk], Bf[kk][1], C1, 0, 0, 0);
        }

#pragma unroll
        for (int r = 0; r < 16; ++r) {
            const int row = (r & 3) + 8 * (r >> 2) + 4 * hi;
            float h0 = fmaxf(C0[r] + bl0, 0.f);
            float h1 = fmaxf(C1[r] + bl1, 0.f);
            float s2 = h0 * h0 + h1 * h1;
#pragma unroll
            for (int off = 16; off > 0; off >>= 1) s2 += __shfl_xor(s2, off);
            const float rn = 1.0f / fmaxf(sqrtf(s2), 1e-12f);
            half2_t o = { (_Float16)(h0 * rn), (_Float16)(h1 * rn) };
            *(half2_t*)(xout + (size_t)(n0 + row) * 64 + 2 * lr) = o;
        }
    }
}

// ---------------------------------------------------------------- post MLP
__global__ __launch_bounds__(256, 2) void k_post(
    const _Float16* __restrict__ x,
    const float* __restrict__ W1, const float* __restrict__ b1,
    const float* __restrict__ W2, const float* __restrict__ b2,
    float* __restrict__ out)
{
    __shared__ __attribute__((aligned(16))) float sIn[4][4][64];
    const int lane = threadIdx.x & 63;
    const int wv   = threadIdx.x >> 6;

    float w1[64], w2[64];
#pragma unroll
    for (int k = 0; k < 64; ++k) w1[k] = W1[k * DD + lane];
#pragma unroll
    for (int k = 0; k < 64; ++k) w2[k] = W2[k * DD + lane];
    const float bl1 = b1[lane];
    const float bl2 = b2[lane];

    const int wt    = (gridDim.x * blockDim.x) >> 6;
    const int wid   = (blockIdx.x * blockDim.x + threadIdx.x) >> 6;
    const int niter = (NN + wt * 4 - 1) / (wt * 4);

    for (int it = 0; it < niter; ++it) {
        const int n0 = (it * wt + wid) * 4;
#pragma unroll
        for (int s = 0; s < 4; ++s) {
            const int n = n0 + s;
            float vx = 0.f;
            if (n < NN) vx = (float)x[n * DD + lane];
            sIn[wv][s][lane] = vx;
        }
        __syncthreads();
#pragma unroll 1
        for (int s = 0; s < 4; ++s) {
            const int n = n0 + s;
            const float4* in4 = (const float4*)(&sIn[wv][s][0]);
            float a0 = 0.f, a1 = 0.f, a2 = 0.f, a3 = 0.f;
#pragma unroll
            for (int k = 0; k < 16; ++k) {
                const float4 v = in4[k];
                a0 = fmaf(v.x, w1[4 * k + 0], a0);
                a1 = fmaf(v.y, w1[4 * k + 1], a1);
                a2 = fmaf(v.z, w1[4 * k + 2], a2);
                a3 = fmaf(v.w, w1[4 * k + 3], a3);
            }
            const float h = fmaxf((a0 + a1) + (a2 + a3) + bl1, 0.f);
            float acc = bl2;
#pragma unroll
            for (int k = 0; k < 64; ++k) acc = fmaf(__shfl(h, k), w2[k], acc);
            if (n < NN) out[n * DD + lane] = acc;
        }
        __syncthreads();
    }
}

// --------------------------------------------------------------------------
extern "C" void kernel_launch(void* const* d_in, const int* in_sizes, int n_in,
                              void* d_out, int out_size, void* d_ws, size_t ws_size,
                              hipStream_t stream)
{
    const float* x_in  = (const float*)d_in[0];
    const float* ea_in = (const float*)d_in[1];
    const int*   ei    = (const int*)d_in[2];
    const float* msg_W = (const float*)d_in[3];
    const float* msg_b = (const float*)d_in[4];
    const float* agg_W = (const float*)d_in[5];
    const float* agg_b = (const float*)d_in[6];
    const float* eup_W = (const float*)d_in[7];
    const float* eup_b = (const float*)d_in[8];
    const float* pW1   = (const float*)d_in[9];
    const float* pb1   = (const float*)d_in[10];
    const float* pW2   = (const float*)d_in[11];
    const float* pb2   = (const float*)d_in[12];
    float* out = (float*)d_out;

    float*    deg  = (float*)d_ws;                       // 100352 f32
    _Float16* agg  = (_Float16*)(deg + 100352);          // NN*64 f16
    _Float16* xb   = agg + (size_t)NN * DD;              // NN*64 f16
    _Float16* eab  = xb + (size_t)NN * DD;               // NE*64 f16
    _Float16* mWf  = eab + (size_t)NE * DD;              // 3*16*512 (frag layout)
    _Float16* aWf  = mWf + 3 * 16 * 512;                 // 3*16*512
    _Float16* eWf  = aWf + 3 * 16 * 512;                 // 3*24*512

    hipMemsetAsync(deg, 0, NN * sizeof(float), stream);
    k_count<<<(NE + 255) / 256, 256, 0, stream>>>(ei + NE, deg);
    k_cvtx<<<(NN * 16 + 255) / 256, 256, 0, stream>>>(x_in, xb);
    k_cvtw<<<(3 * 24 * 512 + 255) / 256, 256, 0, stream>>>(msg_W, agg_W, eup_W,
                                                           mWf, aWf, eWf);

    // ---- layer 0 message + node
    hipMemsetAsync(agg, 0, (size_t)NN * DD * sizeof(_Float16), stream);
    k_msg<1><<<2048, 256, 0, stream>>>(xb, ea_in, ei, mWf, msg_b, agg);
    k_node<<<1024, 256, 0, stream>>>(xb, agg, deg, aWf, agg_b, xb);

    // ---- fused eup0 + msg1 (writes ea1, scatters layer-1 messages)
    hipMemsetAsync(agg, 0, (size_t)NN * DD * sizeof(_Float16), stream);
    k_eupmsg<1, 1><<<2048, 256, 0, stream>>>(
        xb, ea_in, ei,
        eWf, eup_b,                         // eup layer 0 (frag layout)
        mWf + 16 * 512, msg_b + DD,         // msg layer 1
        eab, agg);
    k_node<<<1024, 256, 0, stream>>>(xb, agg, deg,
                                     aWf + 16 * 512, agg_b + DD, xb);

    // ---- fused eup1 + msg2 (ea2 never touches memory)
    hipMemsetAsync(agg, 0, (size_t)NN * DD * sizeof(_Float16), stream);
    k_eupmsg<0, 0><<<2048, 256, 0, stream>>>(
        xb, eab, ei,
        eWf + 24 * 512, eup_b + DD,         // eup layer 1
        mWf + 2 * 16 * 512, msg_b + 2 * DD, // msg layer 2
        nullptr, agg);
    k_node<<<1024, 256, 0, stream>>>(xb, agg, deg,
                                     aWf + 2 * 16 * 512, agg_b + 2 * DD, xb);

    k_post<<<512, 256, 0, stream>>>(xb, pW1, pb1, pW2, pb2, out);
}